// Round 5
// baseline (2876.120 us; speedup 1.0000x reference)
//
#include <hip/hip_runtime.h>

// Problem constants (ManyChannelsIntegrator: C=2, B=256, T=256, N=2048)
#define NN 2048
#define BB 256
#define TT 256
#define CC 2
#define SLOPE 8.0f

#define NBLK 256   // 1 block per CU
#define NTH  512   // 8 waves
#define MT 64      // b-rows per block  (gM = 4)
#define NT 32      // n-cols per block  (gN = 64)

// LDS layout (bytes)
#define LDS_W    0                      // W tile in B-fragment order: 32n x 2048k bf16 = 128 KB
#define LDS_PRE  131072                 // 2 x [64][36] fp32 partial pre  (18432 B)
#define PRE_STRIDE 36
#define LDS_CONST (LDS_PRE + 2*64*PRE_STRIDE*4)
#define LDS_TOTAL (LDS_CONST + 7*32*4) // + per-n constants (mask,bias,thr,enc0,enc1,dec0,dec1)

// ws layout (bytes)
#define WS_FLAGS 0                     // 256 x u32 barrier flags (memset to 0)
#define WS_SBUF0 4096                  // S ping-pong, A-fragment order, 1 MB each
#define WS_SBUF1 (4096 + (1u<<20))
#define WS_PART  (4096 + (2u<<20))     // fp32 partials [T][C][64 bn][256 b] = 33.55 MB

typedef short s16x8 __attribute__((ext_vector_type(8)));      // 8 bf16 (4 VGPRs)
typedef float f32x4 __attribute__((ext_vector_type(4)));
typedef unsigned u32x4 __attribute__((ext_vector_type(4)));   // native vec for inline asm

__device__ __forceinline__ unsigned f2bf1(float f) {
  union { float f; unsigned u; } v; v.f = f;
  return (v.u + 0x7fffu + ((v.u >> 16) & 1u)) >> 16;   // RNE
}
__device__ __forceinline__ unsigned pack2(float a, float b) {
  return f2bf1(a) | (f2bf1(b) << 16);
}

// System-scope (sc0 sc1) 16B store: write-through past L1/L2 to the Infinity
// Cache — device-visible once vmcnt retires, never dirties the local L2.
__device__ __forceinline__ void store_b128_sys(void* p, u32x4 v) {
  asm volatile("global_store_dwordx4 %0, %1, off sc0 sc1" :: "v"(p), "v"(v) : "memory");
}
// Same for a 4B store (partials) — must not leave dirty L2 lines, since the
// per-step buffer_inv discards without writeback.
__device__ __forceinline__ void store_b32_sys(void* p, float v) {
  asm volatile("global_store_dword %0, %1, off sc0 sc1" :: "v"(p), "v"(v) : "memory");
}

// A-load: sc0 only — bypass (stale) L1, ALLOCATE in the XCD L2 so the 32
// blocks/XCD sharing this S strip are served from L2, not the IC.
// Freshness is guaranteed by the per-step agent-acquire fence in the barrier.
#define LOAD_A(dst, base, OFF) \
  asm volatile("global_load_dwordx4 %0, %1, off offset:" #OFF " sc0" \
               : "=v"(dst) : "v"(base) : "memory")

// Grid barrier + single-point L2 invalidate:
//  arrival: drain own stores (vmcnt 0) -> store flag (sc0 sc1)
//  wait:    wave 0 polls all 256 flags (sc0 sc1 loads, don't allocate L2)
//  acquire: wave 0 ONLY issues the agent acquire fence (buffer_inv sc1) —
//           one L2 invalidate per block per step, after ALL producers drained.
__device__ __forceinline__ void grid_barrier(unsigned* flags, unsigned tval) {
  asm volatile("s_waitcnt vmcnt(0)" ::: "memory");
  __syncthreads();
  if (threadIdx.x == 0)
    __hip_atomic_store(&flags[blockIdx.x], tval, __ATOMIC_RELAXED, __HIP_MEMORY_SCOPE_SYSTEM);
  if (threadIdx.x < 64) {
    const int tid = threadIdx.x;
    for (;;) {
      unsigned v0 = __hip_atomic_load(&flags[tid*4+0], __ATOMIC_RELAXED, __HIP_MEMORY_SCOPE_SYSTEM);
      unsigned v1 = __hip_atomic_load(&flags[tid*4+1], __ATOMIC_RELAXED, __HIP_MEMORY_SCOPE_SYSTEM);
      unsigned v2 = __hip_atomic_load(&flags[tid*4+2], __ATOMIC_RELAXED, __HIP_MEMORY_SCOPE_SYSTEM);
      unsigned v3 = __hip_atomic_load(&flags[tid*4+3], __ATOMIC_RELAXED, __HIP_MEMORY_SCOPE_SYSTEM);
      if (__all(v0 >= tval && v1 >= tval && v2 >= tval && v3 >= tval)) break;
      __builtin_amdgcn_s_sleep(1);
    }
  }
  __syncthreads();
  if (threadIdx.x < 64)
    __builtin_amdgcn_fence(__ATOMIC_ACQUIRE, "agent");   // buffer_inv sc1, wave 0 only
  __syncthreads();
}

__global__ __launch_bounds__(NTH, 2)
void mc_integrator_kernel(const float* __restrict__ x, const float* __restrict__ state0,
                          const float* __restrict__ mask, const float* __restrict__ enc,
                          const float* __restrict__ dec, const float* __restrict__ W,
                          const float* __restrict__ bias, const float* __restrict__ thr,
                          char* __restrict__ ws)
{
  extern __shared__ char lds[];
  const int tid = threadIdx.x;
  const int blk = blockIdx.x;
  // blk%8 ~ XCD (heuristic): all 32 blocks on an XCD share the same bm strip,
  // so the XCD L2 serves 31/32 of the S broadcast. Correctness does not depend
  // on the mapping (every block invalidates its own L2 each step).
  const int xcd  = blk & 7;
  const int slot = blk >> 3;
  const int bm = xcd >> 1;                      // 0..3  (64-row strip of b)
  const int bn = slot + ((xcd & 1) << 5);       // 0..63 (32-col strip of n)

  unsigned* flags = (unsigned*)(ws + WS_FLAGS);
  char* sbuf0 = ws + WS_SBUF0;
  char* sbuf1 = ws + WS_SBUF1;
  float* partials = (float*)(ws + WS_PART);     // [t][c][bn][b]

  // ---- stage per-n constants ----
  float* cmask = (float*)(lds + LDS_CONST);
  float* cbias = cmask + 32;  float* cthr  = cbias + 32;
  float* cenc0 = cthr  + 32;  float* cenc1 = cenc0 + 32;
  float* cdec0 = cenc1 + 32;  float* cdec1 = cdec0 + 32;
  if (tid < 32) {
    int n = bn * NT + tid;
    cmask[tid] = mask[n];  cbias[tid] = bias[n];  cthr[tid] = thr[n];
    cenc0[tid] = enc[n];   cenc1[tid] = enc[NN + n];
    cdec0[tid] = dec[n];   cdec1[tid] = dec[NN + n];
  }

  // ---- one-time: W tile -> bf16, LDS, B-fragment order ----
  for (int it = 0; it < 16; ++it) {
    int chunk = tid + it * NTH;          // 0..8191
    int n_local = chunk >> 8;
    int kc = chunk & 255;
    int k = kc * 8;
    const float* src = W + (size_t)(bn * NT + n_local) * NN + k;
    float4 lo = *(const float4*)src;
    float4 hi = *(const float4*)(src + 4);
    u32x4 pk = { pack2(lo.x, lo.y), pack2(lo.z, lo.w),
                 pack2(hi.x, hi.y), pack2(hi.z, hi.w) };
    int kb = k >> 5, quad = (k >> 3) & 3, nf = n_local >> 4;
    int ln = (n_local & 15) + quad * 16;
    *(u32x4*)(lds + LDS_W + ((kb*2 + nf) * 1024 + ln * 16)) = pk;
  }
  __syncthreads();

  // ---- per-thread epilogue roles ----
  const int b_local = (tid & 255) >> 2;          // 0..63
  const int c4      = tid & 3;                   // 0..3 (8-col group of n)
  const int bg      = bm * MT + b_local;         // global b row
  const int nl0     = c4 * 8;
  const int bgi     = bg >> 4;
  const int lane_s  = (bg & 15) + c4 * 16;
  const unsigned s_slot = (unsigned)((bgi * 64 + bn) * 1024 + lane_s * 16);

  // ---- build S_0 = state0 + mask*ext(x_0), fragment order ----
  if (tid < 256) {
    const float* s0 = state0 + (size_t)bg * NN + bn * NT + nl0;
    float4 lo = *(const float4*)s0;
    float4 hi = *(const float4*)(s0 + 4);
    float sv[8] = {lo.x, lo.y, lo.z, lo.w, hi.x, hi.y, hi.z, hi.w};
    float x0 = x[(size_t)bg * TT];
    float x1 = x[(size_t)(BB*TT) + bg * TT];
    #pragma unroll
    for (int j = 0; j < 8; ++j)
      sv[j] += cmask[nl0+j] * (x0 * cenc0[nl0+j] + x1 * cenc1[nl0+j]);
    u32x4 pk = { pack2(sv[0], sv[1]), pack2(sv[2], sv[3]),
                 pack2(sv[4], sv[5]), pack2(sv[6], sv[7]) };
    store_b128_sys(sbuf0 + s_slot, pk);
  }
  grid_barrier(flags, 1);

  // ---- persistent time loop ----
  const int wave = tid >> 6, lane = tid & 63;
  const int msub = wave & 3;      // 16-row group within the 64-row strip
  const int kh   = wave >> 2;     // k-half
  const unsigned a_off = (unsigned)((((bm*4 + msub) * 64) + kh * 32) * 1024 + lane * 16);
  const unsigned w_off = (unsigned)(LDS_W + kh * 32 * 2048 + lane * 16);
  float* pre0 = (float*)(lds + LDS_PRE);
  float* pre1 = pre0 + 64 * PRE_STRIDE;

  for (int t = 0; t < TT; ++t) {
    const char* sb = (t & 1) ? sbuf1 : sbuf0;
    char*       sn = (t & 1) ? sbuf0 : sbuf1;

    // ---- A-phase: 32 L2-cached loads (32 KB/wave in flight), then MFMA ----
    f32x4 acc0 = {0.f, 0.f, 0.f, 0.f};
    f32x4 acc1 = {0.f, 0.f, 0.f, 0.f};
    const char* ap = sb + a_off;
    s16x8 A[32];
    #pragma unroll
    for (int g = 0; g < 8; ++g) {
      const char* base = ap + g * 4096;
      LOAD_A(A[g*4+0], base, 0);
      LOAD_A(A[g*4+1], base, 1024);
      LOAD_A(A[g*4+2], base, 2048);
      LOAD_A(A[g*4+3], base, 3072);
    }
    // first half ready (16 still in flight)
    asm volatile("s_waitcnt vmcnt(16)"
      : "+v"(A[0]), "+v"(A[1]), "+v"(A[2]), "+v"(A[3]),
        "+v"(A[4]), "+v"(A[5]), "+v"(A[6]), "+v"(A[7]),
        "+v"(A[8]), "+v"(A[9]), "+v"(A[10]), "+v"(A[11]),
        "+v"(A[12]), "+v"(A[13]), "+v"(A[14]), "+v"(A[15]));
    #pragma unroll
    for (int i = 0; i < 16; ++i) {
      s16x8 b0 = *(const s16x8*)(lds + w_off + i * 2048);
      s16x8 b1 = *(const s16x8*)(lds + w_off + i * 2048 + 1024);
      acc0 = __builtin_amdgcn_mfma_f32_16x16x32_bf16(A[i], b0, acc0, 0, 0, 0);
      acc1 = __builtin_amdgcn_mfma_f32_16x16x32_bf16(A[i], b1, acc1, 0, 0, 0);
    }
    asm volatile("s_waitcnt vmcnt(0)"
      : "+v"(A[16]), "+v"(A[17]), "+v"(A[18]), "+v"(A[19]),
        "+v"(A[20]), "+v"(A[21]), "+v"(A[22]), "+v"(A[23]),
        "+v"(A[24]), "+v"(A[25]), "+v"(A[26]), "+v"(A[27]),
        "+v"(A[28]), "+v"(A[29]), "+v"(A[30]), "+v"(A[31]));
    #pragma unroll
    for (int i = 16; i < 32; ++i) {
      s16x8 b0 = *(const s16x8*)(lds + w_off + i * 2048);
      s16x8 b1 = *(const s16x8*)(lds + w_off + i * 2048 + 1024);
      acc0 = __builtin_amdgcn_mfma_f32_16x16x32_bf16(A[i], b0, acc0, 0, 0, 0);
      acc1 = __builtin_amdgcn_mfma_f32_16x16x32_bf16(A[i], b1, acc1, 0, 0, 0);
    }

    // stash partial pre tiles (C/D layout: col=lane&15, row=(lane>>4)*4+r)
    {
      float* pre = kh ? pre1 : pre0;
      int col = lane & 15;
      int mbase = msub * 16 + (lane >> 4) * 4;
      #pragma unroll
      for (int r = 0; r < 4; ++r) {
        pre[(mbase + r) * PRE_STRIDE + col]      = acc0[r];
        pre[(mbase + r) * PRE_STRIDE + col + 16] = acc1[r];
      }
    }
    __syncthreads();

    // ---- epilogue: sigmoid, decoder partials, S_{t+1} in fragment order ----
    if (tid < 256) {
      const float* p0r = pre0 + b_local * PRE_STRIDE + nl0;
      const float* p1r = pre1 + b_local * PRE_STRIDE + nl0;
      float4 u0 = *(const float4*)p0r, u1 = *(const float4*)(p0r + 4);
      float4 v0 = *(const float4*)p1r, v1 = *(const float4*)(p1r + 4);
      float pr[8] = {u0.x+v0.x, u0.y+v0.y, u0.z+v0.z, u0.w+v0.w,
                     u1.x+v1.x, u1.y+v1.y, u1.z+v1.z, u1.w+v1.w};
      float st[8];
      float d0 = 0.f, d1 = 0.f;
      #pragma unroll
      for (int j = 0; j < 8; ++j) {
        int nl = nl0 + j;
        float sg = 1.0f / (1.0f + __expf(-SLOPE * (pr[j] - cthr[nl])));
        float s = cmask[nl] * (cbias[nl] + sg);
        st[j] = s;
        d0 += s * cdec0[nl];
        d1 += s * cdec1[nl];
      }
      d0 += __shfl_xor(d0, 1); d0 += __shfl_xor(d0, 2);
      d1 += __shfl_xor(d1, 1); d1 += __shfl_xor(d1, 2);
      if (c4 == 0) {
        store_b32_sys(&partials[((size_t)(t*2 + 0)*64 + bn)*256 + bg], d0);
        store_b32_sys(&partials[((size_t)(t*2 + 1)*64 + bn)*256 + bg], d1);
      }
      if (t < TT - 1) {
        float x0n = x[(size_t)bg * TT + t + 1];
        float x1n = x[(size_t)(BB*TT) + bg * TT + t + 1];
        float sv[8];
        #pragma unroll
        for (int j = 0; j < 8; ++j) {
          int nl = nl0 + j;
          sv[j] = st[j] + cmask[nl] * (x0n * cenc0[nl] + x1n * cenc1[nl]);
        }
        u32x4 pk = { pack2(sv[0], sv[1]), pack2(sv[2], sv[3]),
                     pack2(sv[4], sv[5]), pack2(sv[6], sv[7]) };
        store_b128_sys(sn + s_slot, pk);
      }
    }
    if (t < TT - 1) grid_barrier(flags, (unsigned)(t + 2));
  }
}

// out[c][b][t] = sum_bn partials[t][c][bn][b]
__global__ __launch_bounds__(256)
void reduce_out_kernel(const float* __restrict__ partials, float* __restrict__ out) {
  const int tc = blockIdx.x;          // t*2 + c
  const int b  = threadIdx.x;         // 0..255
  const int t  = tc >> 1, c = tc & 1;
  const float* p = partials + (size_t)tc * 64 * 256 + b;
  float s = 0.f;
  #pragma unroll
  for (int bn = 0; bn < 64; ++bn) s += p[bn * 256];
  out[((size_t)c * BB + b) * TT + t] = s;
}

extern "C" void kernel_launch(void* const* d_in, const int* in_sizes, int n_in,
                              void* d_out, int out_size, void* d_ws, size_t ws_size,
                              hipStream_t stream) {
  const float* x      = (const float*)d_in[0];
  const float* state0 = (const float*)d_in[1];
  const float* mask   = (const float*)d_in[2];
  const float* enc    = (const float*)d_in[3];
  const float* dec    = (const float*)d_in[4];
  const float* W      = (const float*)d_in[5];
  const float* bias   = (const float*)d_in[6];
  const float* thr    = (const float*)d_in[7];
  float* out = (float*)d_out;
  char*  ws  = (char*)d_ws;

  (void)hipMemsetAsync(ws, 0, 4096, stream);   // barrier flags

  (void)hipFuncSetAttribute((const void*)mc_integrator_kernel,
                            hipFuncAttributeMaxDynamicSharedMemorySize, LDS_TOTAL);

  void* args[] = { (void*)&x, (void*)&state0, (void*)&mask, (void*)&enc, (void*)&dec,
                   (void*)&W, (void*)&bias, (void*)&thr, (void*)&ws };
  (void)hipLaunchCooperativeKernel((const void*)mc_integrator_kernel,
                                   dim3(NBLK), dim3(NTH), args, (unsigned)LDS_TOTAL, stream);

  const float* partials = (const float*)(ws + WS_PART);
  reduce_out_kernel<<<dim3(TT*CC), dim3(256), 0, stream>>>(partials, out);
}

// Round 6
// 2505.613 us; speedup vs baseline: 1.1479x; 1.1479x over previous
//
#include <hip/hip_runtime.h>

// Problem constants (ManyChannelsIntegrator: C=2, B=256, T=256, N=2048)
#define NN 2048
#define BB 256
#define TT 256
#define CC 2
#define SLOPE 8.0f

#define NBLK 256   // 1 block per CU
#define NTH  512   // 8 waves
#define MT 64      // b-rows per block  (gM = 4)
#define NT 32      // n-cols per block  (gN = 64)
#define NSB 8      // S-buffer rotation depth (invalidate every NSB steps)

// LDS layout (bytes)
#define LDS_W    0                      // W tile in B-fragment order: 32n x 2048k bf16 = 128 KB
#define LDS_PRE  131072                 // 2 x [64][36] fp32 partial pre  (18432 B)
#define PRE_STRIDE 36
#define LDS_CONST (LDS_PRE + 2*64*PRE_STRIDE*4)
#define LDS_TOTAL (LDS_CONST + 7*32*4) // + per-n constants (mask,bias,thr,enc0,enc1,dec0,dec1)

// ws layout (bytes)
#define WS_FLAGS 0                       // 256 x u32 barrier flags (memset to 0)
#define WS_SBUF  4096                    // 8 x 1 MB S rotation, A-fragment order
#define WS_PART  (4096 + (8u<<20))       // u32-packed bf16 partials [T][64 bn][256 b] = 16.78 MB

typedef short s16x8 __attribute__((ext_vector_type(8)));      // 8 bf16 (4 VGPRs)
typedef float f32x4 __attribute__((ext_vector_type(4)));
typedef unsigned u32x4 __attribute__((ext_vector_type(4)));   // native vec for inline asm

__device__ __forceinline__ unsigned f2bf1(float f) {
  union { float f; unsigned u; } v; v.f = f;
  return (v.u + 0x7fffu + ((v.u >> 16) & 1u)) >> 16;   // RNE
}
__device__ __forceinline__ unsigned pack2(float a, float b) {
  return f2bf1(a) | (f2bf1(b) << 16);
}

// System-scope (sc0 sc1) stores: write-through to the Infinity Cache —
// device-visible once vmcnt retires, never dirties L1/L2 (so buffer_inv,
// which discards without writeback, is always safe).
__device__ __forceinline__ void store_b128_sys(void* p, u32x4 v) {
  asm volatile("global_store_dwordx4 %0, %1, off sc0 sc1" :: "v"(p), "v"(v) : "memory");
}
__device__ __forceinline__ void store_u32_sys(void* p, unsigned v) {
  asm volatile("global_store_dword %0, %1, off sc0 sc1" :: "v"(p), "v"(v) : "memory");
}

// A-load: sc0 — bypass L1, ALLOCATE in the XCD L2 so the 32 blocks/XCD
// sharing this S strip are served from L2 after one IC fill. Freshness across
// buffer reuse (every NSB steps) is guaranteed by the periodic acquire fence.
#define LOAD_A(dst, base, OFF) \
  asm volatile("global_load_dwordx4 %0, %1, off offset:" #OFF " sc0" \
               : "=v"(dst) : "v"(base) : "memory")

// Grid barrier; optionally ends with ONE agent-acquire fence (buffer_inv) —
// only every NSB steps, so the inv latency is amortized 8x vs R5.
__device__ __forceinline__ void grid_barrier(unsigned* flags, unsigned tval, bool do_inv) {
  asm volatile("s_waitcnt vmcnt(0)" ::: "memory");
  __syncthreads();
  if (threadIdx.x == 0)
    __hip_atomic_store(&flags[blockIdx.x], tval, __ATOMIC_RELAXED, __HIP_MEMORY_SCOPE_SYSTEM);
  if (threadIdx.x < 64) {
    const int tid = threadIdx.x;
    for (;;) {
      unsigned v0 = __hip_atomic_load(&flags[tid*4+0], __ATOMIC_RELAXED, __HIP_MEMORY_SCOPE_SYSTEM);
      unsigned v1 = __hip_atomic_load(&flags[tid*4+1], __ATOMIC_RELAXED, __HIP_MEMORY_SCOPE_SYSTEM);
      unsigned v2 = __hip_atomic_load(&flags[tid*4+2], __ATOMIC_RELAXED, __HIP_MEMORY_SCOPE_SYSTEM);
      unsigned v3 = __hip_atomic_load(&flags[tid*4+3], __ATOMIC_RELAXED, __HIP_MEMORY_SCOPE_SYSTEM);
      if (__all(v0 >= tval && v1 >= tval && v2 >= tval && v3 >= tval)) break;
      __builtin_amdgcn_s_sleep(1);
    }
  }
  __syncthreads();
  if (do_inv) {
    if (threadIdx.x < 64)
      __builtin_amdgcn_fence(__ATOMIC_ACQUIRE, "agent");   // buffer_inv, wave 0 only
    __syncthreads();
  }
}

__global__ __launch_bounds__(NTH, 2)
void mc_integrator_kernel(const float* __restrict__ x, const float* __restrict__ state0,
                          const float* __restrict__ mask, const float* __restrict__ enc,
                          const float* __restrict__ dec, const float* __restrict__ W,
                          const float* __restrict__ bias, const float* __restrict__ thr,
                          char* __restrict__ ws)
{
  extern __shared__ char lds[];
  const int tid = threadIdx.x;
  const int blk = blockIdx.x;
  // blk%8 ~ XCD (heuristic): all 32 blocks on an XCD share the same bm strip,
  // so the XCD L2 can serve 31/32 of the S broadcast after one IC fill.
  // Correctness does not depend on the mapping (periodic inv is per-block).
  const int xcd  = blk & 7;
  const int slot = blk >> 3;
  const int bm = xcd >> 1;                      // 0..3  (64-row strip of b)
  const int bn = slot + ((xcd & 1) << 5);       // 0..63 (32-col strip of n)

  unsigned* flags = (unsigned*)(ws + WS_FLAGS);
  char* sbufs = ws + WS_SBUF;                   // 8 x 1 MB rotation
  unsigned* partials = (unsigned*)(ws + WS_PART);  // [t][bn][b] packed (bf16 d0, bf16 d1)

  // ---- stage per-n constants ----
  float* cmask = (float*)(lds + LDS_CONST);
  float* cbias = cmask + 32;  float* cthr  = cbias + 32;
  float* cenc0 = cthr  + 32;  float* cenc1 = cenc0 + 32;
  float* cdec0 = cenc1 + 32;  float* cdec1 = cdec0 + 32;
  if (tid < 32) {
    int n = bn * NT + tid;
    cmask[tid] = mask[n];  cbias[tid] = bias[n];  cthr[tid] = thr[n];
    cenc0[tid] = enc[n];   cenc1[tid] = enc[NN + n];
    cdec0[tid] = dec[n];   cdec1[tid] = dec[NN + n];
  }

  // ---- one-time: W tile -> bf16, LDS, B-fragment order ----
  for (int it = 0; it < 16; ++it) {
    int chunk = tid + it * NTH;          // 0..8191
    int n_local = chunk >> 8;
    int kc = chunk & 255;
    int k = kc * 8;
    const float* src = W + (size_t)(bn * NT + n_local) * NN + k;
    float4 lo = *(const float4*)src;
    float4 hi = *(const float4*)(src + 4);
    u32x4 pk = { pack2(lo.x, lo.y), pack2(lo.z, lo.w),
                 pack2(hi.x, hi.y), pack2(hi.z, hi.w) };
    int kb = k >> 5, quad = (k >> 3) & 3, nf = n_local >> 4;
    int ln = (n_local & 15) + quad * 16;
    *(u32x4*)(lds + LDS_W + ((kb*2 + nf) * 1024 + ln * 16)) = pk;
  }
  __syncthreads();

  // ---- per-thread epilogue roles ----
  const int b_local = (tid & 255) >> 2;          // 0..63
  const int c4      = tid & 3;                   // 0..3 (8-col group of n)
  const int bg      = bm * MT + b_local;         // global b row
  const int nl0     = c4 * 8;
  const int bgi     = bg >> 4;
  const int lane_s  = (bg & 15) + c4 * 16;
  const unsigned s_slot = (unsigned)((bgi * 64 + bn) * 1024 + lane_s * 16);

  // ---- build S_0 = state0 + mask*ext(x_0), fragment order -> sbuf[0] ----
  if (tid < 256) {
    const float* s0 = state0 + (size_t)bg * NN + bn * NT + nl0;
    float4 lo = *(const float4*)s0;
    float4 hi = *(const float4*)(s0 + 4);
    float sv[8] = {lo.x, lo.y, lo.z, lo.w, hi.x, hi.y, hi.z, hi.w};
    float x0 = x[(size_t)bg * TT];
    float x1 = x[(size_t)(BB*TT) + bg * TT];
    #pragma unroll
    for (int j = 0; j < 8; ++j)
      sv[j] += cmask[nl0+j] * (x0 * cenc0[nl0+j] + x1 * cenc1[nl0+j]);
    u32x4 pk = { pack2(sv[0], sv[1]), pack2(sv[2], sv[3]),
                 pack2(sv[4], sv[5]), pack2(sv[6], sv[7]) };
    store_b128_sys(sbufs + s_slot, pk);
  }
  grid_barrier(flags, 1, true);   // inv before step 0 (phase anchor)

  // ---- persistent time loop ----
  const int wave = tid >> 6, lane = tid & 63;
  const int msub = wave & 3;      // 16-row group within the 64-row strip
  const int kh   = wave >> 2;     // k-half
  const unsigned a_off = (unsigned)((((bm*4 + msub) * 64) + kh * 32) * 1024 + lane * 16);
  const unsigned w_off = (unsigned)(LDS_W + kh * 32 * 2048 + lane * 16);
  float* pre0 = (float*)(lds + LDS_PRE);
  float* pre1 = pre0 + 64 * PRE_STRIDE;

  for (int t = 0; t < TT; ++t) {
    const char* sb = sbufs + ((unsigned)(t & (NSB-1)) << 20);        // read S_t
    char*       sn = sbufs + ((unsigned)((t+1) & (NSB-1)) << 20);    // write S_{t+1}

    // ---- A-phase: 32 L2-cached loads (32 KB/wave in flight), then MFMA ----
    f32x4 acc0 = {0.f, 0.f, 0.f, 0.f};
    f32x4 acc1 = {0.f, 0.f, 0.f, 0.f};
    const char* ap = sb + a_off;
    s16x8 A[32];
    #pragma unroll
    for (int g = 0; g < 8; ++g) {
      const char* base = ap + g * 4096;
      LOAD_A(A[g*4+0], base, 0);
      LOAD_A(A[g*4+1], base, 1024);
      LOAD_A(A[g*4+2], base, 2048);
      LOAD_A(A[g*4+3], base, 3072);
    }
    // first half ready (16 still in flight)
    asm volatile("s_waitcnt vmcnt(16)"
      : "+v"(A[0]), "+v"(A[1]), "+v"(A[2]), "+v"(A[3]),
        "+v"(A[4]), "+v"(A[5]), "+v"(A[6]), "+v"(A[7]),
        "+v"(A[8]), "+v"(A[9]), "+v"(A[10]), "+v"(A[11]),
        "+v"(A[12]), "+v"(A[13]), "+v"(A[14]), "+v"(A[15]));
    #pragma unroll
    for (int i = 0; i < 16; ++i) {
      s16x8 b0 = *(const s16x8*)(lds + w_off + i * 2048);
      s16x8 b1 = *(const s16x8*)(lds + w_off + i * 2048 + 1024);
      acc0 = __builtin_amdgcn_mfma_f32_16x16x32_bf16(A[i], b0, acc0, 0, 0, 0);
      acc1 = __builtin_amdgcn_mfma_f32_16x16x32_bf16(A[i], b1, acc1, 0, 0, 0);
    }
    asm volatile("s_waitcnt vmcnt(0)"
      : "+v"(A[16]), "+v"(A[17]), "+v"(A[18]), "+v"(A[19]),
        "+v"(A[20]), "+v"(A[21]), "+v"(A[22]), "+v"(A[23]),
        "+v"(A[24]), "+v"(A[25]), "+v"(A[26]), "+v"(A[27]),
        "+v"(A[28]), "+v"(A[29]), "+v"(A[30]), "+v"(A[31]));
    #pragma unroll
    for (int i = 16; i < 32; ++i) {
      s16x8 b0 = *(const s16x8*)(lds + w_off + i * 2048);
      s16x8 b1 = *(const s16x8*)(lds + w_off + i * 2048 + 1024);
      acc0 = __builtin_amdgcn_mfma_f32_16x16x32_bf16(A[i], b0, acc0, 0, 0, 0);
      acc1 = __builtin_amdgcn_mfma_f32_16x16x32_bf16(A[i], b1, acc1, 0, 0, 0);
    }

    // stash partial pre tiles (C/D layout: col=lane&15, row=(lane>>4)*4+r)
    {
      float* pre = kh ? pre1 : pre0;
      int col = lane & 15;
      int mbase = msub * 16 + (lane >> 4) * 4;
      #pragma unroll
      for (int r = 0; r < 4; ++r) {
        pre[(mbase + r) * PRE_STRIDE + col]      = acc0[r];
        pre[(mbase + r) * PRE_STRIDE + col + 16] = acc1[r];
      }
    }
    __syncthreads();

    // ---- epilogue: sigmoid, decoder partials, S_{t+1} in fragment order ----
    if (tid < 256) {
      const float* p0r = pre0 + b_local * PRE_STRIDE + nl0;
      const float* p1r = pre1 + b_local * PRE_STRIDE + nl0;
      float4 u0 = *(const float4*)p0r, u1 = *(const float4*)(p0r + 4);
      float4 v0 = *(const float4*)p1r, v1 = *(const float4*)(p1r + 4);
      float pr[8] = {u0.x+v0.x, u0.y+v0.y, u0.z+v0.z, u0.w+v0.w,
                     u1.x+v1.x, u1.y+v1.y, u1.z+v1.z, u1.w+v1.w};
      float st[8];
      float d0 = 0.f, d1 = 0.f;
      #pragma unroll
      for (int j = 0; j < 8; ++j) {
        int nl = nl0 + j;
        float sg = 1.0f / (1.0f + __expf(-SLOPE * (pr[j] - cthr[nl])));
        float s = cmask[nl] * (cbias[nl] + sg);
        st[j] = s;
        d0 += s * cdec0[nl];
        d1 += s * cdec1[nl];
      }
      d0 += __shfl_xor(d0, 1); d0 += __shfl_xor(d0, 2);
      d1 += __shfl_xor(d1, 1); d1 += __shfl_xor(d1, 2);
      if (c4 == 0)
        store_u32_sys(&partials[((size_t)t*64 + bn)*256 + bg], pack2(d0, d1));
      if (t < TT - 1) {
        float x0n = x[(size_t)bg * TT + t + 1];
        float x1n = x[(size_t)(BB*TT) + bg * TT + t + 1];
        float sv[8];
        #pragma unroll
        for (int j = 0; j < 8; ++j) {
          int nl = nl0 + j;
          sv[j] = st[j] + cmask[nl] * (x0n * cenc0[nl] + x1n * cenc1[nl]);
        }
        u32x4 pk = { pack2(sv[0], sv[1]), pack2(sv[2], sv[3]),
                     pack2(sv[4], sv[5]), pack2(sv[6], sv[7]) };
        store_b128_sys(sn + s_slot, pk);
      }
    }
    // Invalidate only when entering a step that reuses a rotated buffer
    // (every NSB steps): lines cached at step t' are killed at the next
    // multiple of NSB, which is <= their re-read at t'+NSB.
    if (t < TT - 1) grid_barrier(flags, (unsigned)(t + 2), ((t + 1) & (NSB-1)) == 0);
  }
}

// out[c][b][t] = sum_bn unpack(partials[t][bn][b])
__global__ __launch_bounds__(256)
void reduce_out_kernel(const unsigned* __restrict__ partials, float* __restrict__ out) {
  const int t = blockIdx.x;           // 0..255
  const int b = threadIdx.x;          // 0..255
  const unsigned* p = partials + (size_t)t * 64 * 256 + b;
  float s0 = 0.f, s1 = 0.f;
  #pragma unroll
  for (int bn = 0; bn < 64; ++bn) {
    unsigned v = p[bn * 256];
    union { unsigned u; float f; } lo, hi;
    lo.u = v << 16; hi.u = v & 0xffff0000u;
    s0 += lo.f; s1 += hi.f;
  }
  out[(size_t)b * TT + t] = s0;
  out[(size_t)(BB * TT) + (size_t)b * TT + t] = s1;
}

extern "C" void kernel_launch(void* const* d_in, const int* in_sizes, int n_in,
                              void* d_out, int out_size, void* d_ws, size_t ws_size,
                              hipStream_t stream) {
  const float* x      = (const float*)d_in[0];
  const float* state0 = (const float*)d_in[1];
  const float* mask   = (const float*)d_in[2];
  const float* enc    = (const float*)d_in[3];
  const float* dec    = (const float*)d_in[4];
  const float* W      = (const float*)d_in[5];
  const float* bias   = (const float*)d_in[6];
  const float* thr    = (const float*)d_in[7];
  float* out = (float*)d_out;
  char*  ws  = (char*)d_ws;

  (void)hipMemsetAsync(ws, 0, 4096, stream);   // barrier flags

  (void)hipFuncSetAttribute((const void*)mc_integrator_kernel,
                            hipFuncAttributeMaxDynamicSharedMemorySize, LDS_TOTAL);

  void* args[] = { (void*)&x, (void*)&state0, (void*)&mask, (void*)&enc, (void*)&dec,
                   (void*)&W, (void*)&bias, (void*)&thr, (void*)&ws };
  (void)hipLaunchCooperativeKernel((const void*)mc_integrator_kernel,
                                   dim3(NBLK), dim3(NTH), args, (unsigned)LDS_TOTAL, stream);

  const unsigned* partials = (const unsigned*)(ws + WS_PART);
  reduce_out_kernel<<<dim3(TT), dim3(256), 0, stream>>>(partials, out);
}

// Round 7
// 2431.519 us; speedup vs baseline: 1.1828x; 1.0305x over previous
//
#include <hip/hip_runtime.h>

// Problem constants (ManyChannelsIntegrator: C=2, B=256, T=256, N=2048)
#define NN 2048
#define BB 256
#define TT 256
#define CC 2
#define SLOPE 8.0f

#define NBLK 256   // 1 block per CU
#define NTH  512   // 8 waves
#define MT 64      // b-rows per block  (gM = 4)
#define NT 32      // n-cols per block  (gN = 64)
#define NSB 8      // S-buffer rotation depth (invalidate every NSB steps)

// LDS layout (bytes)
#define LDS_W    0                      // W tile in B-fragment order: 32n x 2048k bf16 = 128 KB
#define LDS_PRE  131072                 // 2 x [64][36] fp32 partial pre  (18432 B)
#define PRE_STRIDE 36
#define LDS_CONST (LDS_PRE + 2*64*PRE_STRIDE*4)
#define LDS_TOTAL (LDS_CONST + 7*32*4) // + per-n constants (mask,bias,thr,enc0,enc1,dec0,dec1)

// ws layout (bytes)
#define WS_FLAGS 0                       // 256 x u32 barrier flags (memset to 0)
#define WS_SBUF  4096                    // 8 x 1 MB S rotation, A-fragment order
#define WS_PART  (4096 + (8u<<20))       // u32-packed bf16 partials [T][64 bn][256 b] = 16.78 MB

typedef short s16x8 __attribute__((ext_vector_type(8)));      // 8 bf16 (4 VGPRs)
typedef float f32x4 __attribute__((ext_vector_type(4)));
typedef unsigned u32x4 __attribute__((ext_vector_type(4)));   // native vec for inline asm

__device__ __forceinline__ unsigned f2bf1(float f) {
  union { float f; unsigned u; } v; v.f = f;
  return (v.u + 0x7fffu + ((v.u >> 16) & 1u)) >> 16;   // RNE
}
__device__ __forceinline__ unsigned pack2(float a, float b) {
  return f2bf1(a) | (f2bf1(b) << 16);
}

// System-scope (sc0 sc1) stores: write-through to the Infinity Cache —
// device-visible once vmcnt retires, never dirties L1/L2 (so buffer_inv,
// which discards without writeback, is always safe).
__device__ __forceinline__ void store_b128_sys(void* p, u32x4 v) {
  asm volatile("global_store_dwordx4 %0, %1, off sc0 sc1" :: "v"(p), "v"(v) : "memory");
}
__device__ __forceinline__ void store_u32_sys(void* p, unsigned v) {
  asm volatile("global_store_dword %0, %1, off sc0 sc1" :: "v"(p), "v"(v) : "memory");
}

// A-load: PLAIN (no sc bits) — allocate in L1 and the XCD L2. R6 showed sc0
// loads behave like IC-direct (agent coherence forces an L2 bypass); plain
// loads are the only path that actually dedups the broadcast in L2/L1.
// Freshness across buffer reuse (every NSB steps) is guaranteed by the
// periodic agent-acquire fence (L1+L2 invalidate) aligned with the rotation.
#define LOAD_A(dst, base, OFF) \
  asm volatile("global_load_dwordx4 %0, %1, off offset:" #OFF \
               : "=v"(dst) : "v"(base) : "memory")

// Grid barrier; optionally ends with ONE agent-acquire fence (buffer_inv) —
// only every NSB steps, so the inv latency is amortized 8x.
__device__ __forceinline__ void grid_barrier(unsigned* flags, unsigned tval, bool do_inv) {
  asm volatile("s_waitcnt vmcnt(0)" ::: "memory");
  __syncthreads();
  if (threadIdx.x == 0)
    __hip_atomic_store(&flags[blockIdx.x], tval, __ATOMIC_RELAXED, __HIP_MEMORY_SCOPE_SYSTEM);
  if (threadIdx.x < 64) {
    const int tid = threadIdx.x;
    for (;;) {
      unsigned v0 = __hip_atomic_load(&flags[tid*4+0], __ATOMIC_RELAXED, __HIP_MEMORY_SCOPE_SYSTEM);
      unsigned v1 = __hip_atomic_load(&flags[tid*4+1], __ATOMIC_RELAXED, __HIP_MEMORY_SCOPE_SYSTEM);
      unsigned v2 = __hip_atomic_load(&flags[tid*4+2], __ATOMIC_RELAXED, __HIP_MEMORY_SCOPE_SYSTEM);
      unsigned v3 = __hip_atomic_load(&flags[tid*4+3], __ATOMIC_RELAXED, __HIP_MEMORY_SCOPE_SYSTEM);
      if (__all(v0 >= tval && v1 >= tval && v2 >= tval && v3 >= tval)) break;
      __builtin_amdgcn_s_sleep(1);
    }
  }
  __syncthreads();
  if (do_inv) {
    if (threadIdx.x < 64)
      __builtin_amdgcn_fence(__ATOMIC_ACQUIRE, "agent");   // L1+L2 inv, wave 0 only
    __syncthreads();
  }
}

__global__ __launch_bounds__(NTH, 2)
void mc_integrator_kernel(const float* __restrict__ x, const float* __restrict__ state0,
                          const float* __restrict__ mask, const float* __restrict__ enc,
                          const float* __restrict__ dec, const float* __restrict__ W,
                          const float* __restrict__ bias, const float* __restrict__ thr,
                          char* __restrict__ ws)
{
  extern __shared__ char lds[];
  const int tid = threadIdx.x;
  const int blk = blockIdx.x;
  // blk%8 ~ XCD (heuristic): blocks sharing a bm strip cluster on few XCDs,
  // so each XCD L2 serves most of the S broadcast after one IC fill.
  // Correctness does not depend on the mapping (periodic inv is per-block).
  const int xcd  = blk & 7;
  const int slot = blk >> 3;
  const int bm = xcd >> 1;                      // 0..3  (64-row strip of b)
  const int bn = slot + ((xcd & 1) << 5);       // 0..63 (32-col strip of n)

  unsigned* flags = (unsigned*)(ws + WS_FLAGS);
  char* sbufs = ws + WS_SBUF;                   // 8 x 1 MB rotation
  unsigned* partials = (unsigned*)(ws + WS_PART);  // [t][bn][b] packed (bf16 d0, bf16 d1)

  // ---- stage per-n constants ----
  float* cmask = (float*)(lds + LDS_CONST);
  float* cbias = cmask + 32;  float* cthr  = cbias + 32;
  float* cenc0 = cthr  + 32;  float* cenc1 = cenc0 + 32;
  float* cdec0 = cenc1 + 32;  float* cdec1 = cdec0 + 32;
  if (tid < 32) {
    int n = bn * NT + tid;
    cmask[tid] = mask[n];  cbias[tid] = bias[n];  cthr[tid] = thr[n];
    cenc0[tid] = enc[n];   cenc1[tid] = enc[NN + n];
    cdec0[tid] = dec[n];   cdec1[tid] = dec[NN + n];
  }

  // ---- one-time: W tile -> bf16, LDS, B-fragment order ----
  for (int it = 0; it < 16; ++it) {
    int chunk = tid + it * NTH;          // 0..8191
    int n_local = chunk >> 8;
    int kc = chunk & 255;
    int k = kc * 8;
    const float* src = W + (size_t)(bn * NT + n_local) * NN + k;
    float4 lo = *(const float4*)src;
    float4 hi = *(const float4*)(src + 4);
    u32x4 pk = { pack2(lo.x, lo.y), pack2(lo.z, lo.w),
                 pack2(hi.x, hi.y), pack2(hi.z, hi.w) };
    int kb = k >> 5, quad = (k >> 3) & 3, nf = n_local >> 4;
    int ln = (n_local & 15) + quad * 16;
    *(u32x4*)(lds + LDS_W + ((kb*2 + nf) * 1024 + ln * 16)) = pk;
  }
  __syncthreads();

  // ---- per-thread epilogue roles ----
  const int b_local = (tid & 255) >> 2;          // 0..63
  const int c4      = tid & 3;                   // 0..3 (8-col group of n)
  const int bg      = bm * MT + b_local;         // global b row
  const int nl0     = c4 * 8;
  const int bgi     = bg >> 4;
  const int lane_s  = (bg & 15) + c4 * 16;
  const unsigned s_slot = (unsigned)((bgi * 64 + bn) * 1024 + lane_s * 16);

  // ---- build S_0 = state0 + mask*ext(x_0), fragment order -> sbuf[0] ----
  if (tid < 256) {
    const float* s0 = state0 + (size_t)bg * NN + bn * NT + nl0;
    float4 lo = *(const float4*)s0;
    float4 hi = *(const float4*)(s0 + 4);
    float sv[8] = {lo.x, lo.y, lo.z, lo.w, hi.x, hi.y, hi.z, hi.w};
    float x0 = x[(size_t)bg * TT];
    float x1 = x[(size_t)(BB*TT) + bg * TT];
    #pragma unroll
    for (int j = 0; j < 8; ++j)
      sv[j] += cmask[nl0+j] * (x0 * cenc0[nl0+j] + x1 * cenc1[nl0+j]);
    u32x4 pk = { pack2(sv[0], sv[1]), pack2(sv[2], sv[3]),
                 pack2(sv[4], sv[5]), pack2(sv[6], sv[7]) };
    store_b128_sys(sbufs + s_slot, pk);
  }
  grid_barrier(flags, 1, true);   // inv before step 0 (phase anchor)

  // ---- persistent time loop ----
  const int wave = tid >> 6, lane = tid & 63;
  const int msub = wave & 3;      // 16-row group within the 64-row strip
  const int kh   = wave >> 2;     // k-half
  const unsigned a_off = (unsigned)((((bm*4 + msub) * 64) + kh * 32) * 1024 + lane * 16);
  const unsigned w_off = (unsigned)(LDS_W + kh * 32 * 2048 + lane * 16);
  float* pre0 = (float*)(lds + LDS_PRE);
  float* pre1 = pre0 + 64 * PRE_STRIDE;

  for (int t = 0; t < TT; ++t) {
    const char* sb = sbufs + ((unsigned)(t & (NSB-1)) << 20);        // read S_t
    char*       sn = sbufs + ((unsigned)((t+1) & (NSB-1)) << 20);    // write S_{t+1}

    // ---- A-phase: 32 cached loads (32 KB/wave in flight), then MFMA ----
    f32x4 acc0 = {0.f, 0.f, 0.f, 0.f};
    f32x4 acc1 = {0.f, 0.f, 0.f, 0.f};
    const char* ap = sb + a_off;
    s16x8 A[32];
    #pragma unroll
    for (int g = 0; g < 8; ++g) {
      const char* base = ap + g * 4096;
      LOAD_A(A[g*4+0], base, 0);
      LOAD_A(A[g*4+1], base, 1024);
      LOAD_A(A[g*4+2], base, 2048);
      LOAD_A(A[g*4+3], base, 3072);
    }
    // first half ready (16 still in flight)
    asm volatile("s_waitcnt vmcnt(16)"
      : "+v"(A[0]), "+v"(A[1]), "+v"(A[2]), "+v"(A[3]),
        "+v"(A[4]), "+v"(A[5]), "+v"(A[6]), "+v"(A[7]),
        "+v"(A[8]), "+v"(A[9]), "+v"(A[10]), "+v"(A[11]),
        "+v"(A[12]), "+v"(A[13]), "+v"(A[14]), "+v"(A[15]));
    #pragma unroll
    for (int i = 0; i < 16; ++i) {
      s16x8 b0 = *(const s16x8*)(lds + w_off + i * 2048);
      s16x8 b1 = *(const s16x8*)(lds + w_off + i * 2048 + 1024);
      acc0 = __builtin_amdgcn_mfma_f32_16x16x32_bf16(A[i], b0, acc0, 0, 0, 0);
      acc1 = __builtin_amdgcn_mfma_f32_16x16x32_bf16(A[i], b1, acc1, 0, 0, 0);
    }
    asm volatile("s_waitcnt vmcnt(0)"
      : "+v"(A[16]), "+v"(A[17]), "+v"(A[18]), "+v"(A[19]),
        "+v"(A[20]), "+v"(A[21]), "+v"(A[22]), "+v"(A[23]),
        "+v"(A[24]), "+v"(A[25]), "+v"(A[26]), "+v"(A[27]),
        "+v"(A[28]), "+v"(A[29]), "+v"(A[30]), "+v"(A[31]));
    #pragma unroll
    for (int i = 16; i < 32; ++i) {
      s16x8 b0 = *(const s16x8*)(lds + w_off + i * 2048);
      s16x8 b1 = *(const s16x8*)(lds + w_off + i * 2048 + 1024);
      acc0 = __builtin_amdgcn_mfma_f32_16x16x32_bf16(A[i], b0, acc0, 0, 0, 0);
      acc1 = __builtin_amdgcn_mfma_f32_16x16x32_bf16(A[i], b1, acc1, 0, 0, 0);
    }

    // stash partial pre tiles (C/D layout: col=lane&15, row=(lane>>4)*4+r)
    {
      float* pre = kh ? pre1 : pre0;
      int col = lane & 15;
      int mbase = msub * 16 + (lane >> 4) * 4;
      #pragma unroll
      for (int r = 0; r < 4; ++r) {
        pre[(mbase + r) * PRE_STRIDE + col]      = acc0[r];
        pre[(mbase + r) * PRE_STRIDE + col + 16] = acc1[r];
      }
    }
    __syncthreads();

    // ---- epilogue: sigmoid, decoder partials, S_{t+1} in fragment order ----
    if (tid < 256) {
      const float* p0r = pre0 + b_local * PRE_STRIDE + nl0;
      const float* p1r = pre1 + b_local * PRE_STRIDE + nl0;
      float4 u0 = *(const float4*)p0r, u1 = *(const float4*)(p0r + 4);
      float4 v0 = *(const float4*)p1r, v1 = *(const float4*)(p1r + 4);
      float pr[8] = {u0.x+v0.x, u0.y+v0.y, u0.z+v0.z, u0.w+v0.w,
                     u1.x+v1.x, u1.y+v1.y, u1.z+v1.z, u1.w+v1.w};
      float st[8];
      float d0 = 0.f, d1 = 0.f;
      #pragma unroll
      for (int j = 0; j < 8; ++j) {
        int nl = nl0 + j;
        float sg = 1.0f / (1.0f + __expf(-SLOPE * (pr[j] - cthr[nl])));
        float s = cmask[nl] * (cbias[nl] + sg);
        st[j] = s;
        d0 += s * cdec0[nl];
        d1 += s * cdec1[nl];
      }
      d0 += __shfl_xor(d0, 1); d0 += __shfl_xor(d0, 2);
      d1 += __shfl_xor(d1, 1); d1 += __shfl_xor(d1, 2);
      if (c4 == 0)
        store_u32_sys(&partials[((size_t)t*64 + bn)*256 + bg], pack2(d0, d1));
      if (t < TT - 1) {
        float x0n = x[(size_t)bg * TT + t + 1];
        float x1n = x[(size_t)(BB*TT) + bg * TT + t + 1];
        float sv[8];
        #pragma unroll
        for (int j = 0; j < 8; ++j) {
          int nl = nl0 + j;
          sv[j] = st[j] + cmask[nl] * (x0n * cenc0[nl] + x1n * cenc1[nl]);
        }
        u32x4 pk = { pack2(sv[0], sv[1]), pack2(sv[2], sv[3]),
                     pack2(sv[4], sv[5]), pack2(sv[6], sv[7]) };
        store_b128_sys(sn + s_slot, pk);
      }
    }
    // Invalidate only when entering a step that reuses a rotated buffer
    // (every NSB steps): lines cached at step t' are killed at the next
    // multiple of NSB, which is <= their re-read at t'+NSB, and the slot
    // being entered is rewritten strictly after the inv.
    if (t < TT - 1) grid_barrier(flags, (unsigned)(t + 2), ((t + 1) & (NSB-1)) == 0);
  }
}

// out[c][b][t] = sum_bn unpack(partials[t][bn][b])
__global__ __launch_bounds__(256)
void reduce_out_kernel(const unsigned* __restrict__ partials, float* __restrict__ out) {
  const int t = blockIdx.x;           // 0..255
  const int b = threadIdx.x;          // 0..255
  const unsigned* p = partials + (size_t)t * 64 * 256 + b;
  float s0 = 0.f, s1 = 0.f;
  #pragma unroll
  for (int bn = 0; bn < 64; ++bn) {
    unsigned v = p[bn * 256];
    union { unsigned u; float f; } lo, hi;
    lo.u = v << 16; hi.u = v & 0xffff0000u;
    s0 += lo.f; s1 += hi.f;
  }
  out[(size_t)b * TT + t] = s0;
  out[(size_t)(BB * TT) + (size_t)b * TT + t] = s1;
}

extern "C" void kernel_launch(void* const* d_in, const int* in_sizes, int n_in,
                              void* d_out, int out_size, void* d_ws, size_t ws_size,
                              hipStream_t stream) {
  const float* x      = (const float*)d_in[0];
  const float* state0 = (const float*)d_in[1];
  const float* mask   = (const float*)d_in[2];
  const float* enc    = (const float*)d_in[3];
  const float* dec    = (const float*)d_in[4];
  const float* W      = (const float*)d_in[5];
  const float* bias   = (const float*)d_in[6];
  const float* thr    = (const float*)d_in[7];
  float* out = (float*)d_out;
  char*  ws  = (char*)d_ws;

  (void)hipMemsetAsync(ws, 0, 4096, stream);   // barrier flags

  (void)hipFuncSetAttribute((const void*)mc_integrator_kernel,
                            hipFuncAttributeMaxDynamicSharedMemorySize, LDS_TOTAL);

  void* args[] = { (void*)&x, (void*)&state0, (void*)&mask, (void*)&enc, (void*)&dec,
                   (void*)&W, (void*)&bias, (void*)&thr, (void*)&ws };
  (void)hipLaunchCooperativeKernel((const void*)mc_integrator_kernel,
                                   dim3(NBLK), dim3(NTH), args, (unsigned)LDS_TOTAL, stream);

  const unsigned* partials = (const unsigned*)(ws + WS_PART);
  reduce_out_kernel<<<dim3(TT), dim3(256), 0, stream>>>(partials, out);
}